// Round 1
// baseline (628.803 us; speedup 1.0000x reference)
//
#include <hip/hip_runtime.h>
#include <stdint.h>

// Problem constants (fixed by the reference)
#define E_N   500000
#define G_N   25000
#define HIDN  128
#define KIN   272
#define KPAD  288   // 9 * 32
#define NKSTEP 9

typedef short bfrag_t __attribute__((ext_vector_type(8)));  // 8 bf16 = 4 VGPRs
typedef float accf4  __attribute__((ext_vector_type(4)));   // 4 f32 acc

__device__ __forceinline__ uint32_t pack2_bf16(float a, float b) {
    uint32_t ua = __builtin_bit_cast(uint32_t, a);
    uint32_t ub = __builtin_bit_cast(uint32_t, b);
    ua += 0x7FFFu + ((ua >> 16) & 1u);   // RNE
    ub += 0x7FFFu + ((ub >> 16) & 1u);
    return (ua >> 16) | (ub & 0xFFFF0000u);
}

// ---------------- prep: zero seg_sum, build Wb[n][k] = bf16(W1[k][n]), k-padded to 288
__global__ void prep_kernel(const float* __restrict__ W1, float* __restrict__ seg_sum,
                            ushort* __restrict__ Wb) {
    int t = blockIdx.x * 256 + threadIdx.x;
    if (t < G_N) seg_sum[t] = 0.0f;
    if (t < HIDN * KPAD) {
        int n = t / KPAD;
        int k = t - n * KPAD;
        ushort v = 0;
        if (k < KIN) {
            uint32_t u = __builtin_bit_cast(uint32_t, W1[k * HIDN + n]);
            u += 0x7FFFu + ((u >> 16) & 1u);
            v = (ushort)(u >> 16);
        }
        Wb[t] = v;
    }
}

// ---------------- main: fused MLP (GEMM1 + relu + GEMM2) + exp + segment-sum
// BM=256 rows/block, 4 waves x 64 rows, N=128 full, BK=32, K padded to 288.
__launch_bounds__(256, 2)
__global__ void mlp_kernel(const float* __restrict__ src, const float* __restrict__ dst,
                           const float* __restrict__ attr, const ushort* __restrict__ Wb,
                           const float* __restrict__ b1, const float* __restrict__ W2,
                           const float* __restrict__ b2, const int* __restrict__ gidx,
                           float* __restrict__ logits_out, float* __restrict__ ex_out,
                           float* __restrict__ seg_sum) {
    __shared__ __align__(16) ushort Alds[256 * 32];  // 16 KB: [row][k] bf16
    __shared__ __align__(16) ushort Blds[128 * 32];  //  8 KB: [n][k]  bf16

    const int tid  = threadIdx.x;
    const int lane = tid & 63;
    const int wave = tid >> 6;
    const int blk_row = blockIdx.x * 256;

    accf4 acc[4][8];
    #pragma unroll
    for (int a = 0; a < 4; ++a)
        #pragma unroll
        for (int b = 0; b < 8; ++b)
            acc[a][b] = (accf4)(0.0f);

    const int rsub = tid >> 3;   // 0..31 : row sub-index within a 32-row band
    const int col4 = tid & 7;    // 0..7  : float4 column within the 32-wide K slice

    for (int s = 0; s < NKSTEP; ++s) {
        __syncthreads();   // protect LDS from overwrite while prior step computes

        // ---- stage A: 256 rows x 32 f32 -> bf16 LDS (each thread: 8 float4)
        const float* bp; int rstride; bool vcol;
        if (s < 4)      { bp = src  + s * 32 + col4 * 4;        rstride = 128; vcol = true; }
        else if (s < 8) { bp = dst  + (s - 4) * 32 + col4 * 4;  rstride = 128; vcol = true; }
        else            { bp = attr + col4 * 4;                 rstride = 16;  vcol = (col4 < 4); }

        #pragma unroll
        for (int j = 0; j < 8; ++j) {
            int rl = j * 32 + rsub;           // local row 0..255
            int grow = blk_row + rl;
            float4 v = {0.f, 0.f, 0.f, 0.f};
            if (vcol && grow < E_N) v = *(const float4*)(bp + (size_t)grow * rstride);
            uint2 p;
            p.x = pack2_bf16(v.x, v.y);
            p.y = pack2_bf16(v.z, v.w);
            *(uint2*)&Alds[rl * 32 + col4 * 4] = p;
        }

        // ---- stage B: 128 x 32 bf16 from Wb (each thread: 2 x 16B)
        #pragma unroll
        for (int i = 0; i < 2; ++i) {
            int c  = i * 256 + tid;           // 16B chunk index, 512 total
            int n  = c >> 2;
            int ko = (c & 3) * 8;
            uint4 w = *(const uint4*)(Wb + n * KPAD + s * 32 + ko);
            *(uint4*)&Blds[c * 8] = w;        // flat == [n][k] layout
        }

        __syncthreads();

        // ---- compute: wave handles rows [wave*64, wave*64+64), all 128 cols
        bfrag_t afrag[4];
        #pragma unroll
        for (int a = 0; a < 4; ++a)
            afrag[a] = *(const bfrag_t*)&Alds[(wave * 64 + a * 16 + (lane & 15)) * 32 + (lane >> 4) * 8];
        #pragma unroll
        for (int b = 0; b < 8; ++b) {
            bfrag_t bfrag = *(const bfrag_t*)&Blds[(b * 16 + (lane & 15)) * 32 + (lane >> 4) * 8];
            #pragma unroll
            for (int a = 0; a < 4; ++a)
                acc[a][b] = __builtin_amdgcn_mfma_f32_16x16x32_bf16(afrag[a], bfrag, acc[a][b], 0, 0, 0);
        }
    }

    // ---- epilogue: h = relu(acc + b1); logit = h . W2 + b2 (f32 throughout)
    const int cbase = lane & 15;   // column sub-index (n)
    const int quad  = lane >> 4;
    float w2v[8], b1v[8];
    #pragma unroll
    for (int b = 0; b < 8; ++b) {
        w2v[b] = W2[b * 16 + cbase];
        b1v[b] = b1[b * 16 + cbase];
    }
    const float bias2 = b2[0];

    #pragma unroll
    for (int a = 0; a < 4; ++a) {
        float p[4] = {0.f, 0.f, 0.f, 0.f};
        #pragma unroll
        for (int b = 0; b < 8; ++b) {
            #pragma unroll
            for (int r = 0; r < 4; ++r) {
                float h = acc[a][b][r] + b1v[b];
                h = h > 0.f ? h : 0.f;
                p[r] += h * w2v[b];
            }
        }
        #pragma unroll
        for (int r = 0; r < 4; ++r) {
            float v = p[r];
            v += __shfl_xor(v, 1);   // reduce across the 16 column-lanes
            v += __shfl_xor(v, 2);
            v += __shfl_xor(v, 4);
            v += __shfl_xor(v, 8);
            if (cbase == 0) {
                int grow = blk_row + wave * 64 + a * 16 + quad * 4 + r;
                if (grow < E_N) {
                    float logit = v + bias2;
                    logits_out[grow] = logit;
                    float ex = __expf(logit);   // no max-subtraction: |logit| < ~5
                    ex_out[grow] = ex;
                    atomicAdd(&seg_sum[gidx[grow]], ex);
                }
            }
        }
    }
}

// ---------------- normalize: weight = ex / seg_sum[g]
__global__ void norm_kernel(const float* __restrict__ ex, const float* __restrict__ seg_sum,
                            const int* __restrict__ gidx, float* __restrict__ wout) {
    int e = blockIdx.x * 256 + threadIdx.x;
    if (e < E_N) wout[e] = ex[e] / seg_sum[gidx[e]];
}

extern "C" void kernel_launch(void* const* d_in, const int* in_sizes, int n_in,
                              void* d_out, int out_size, void* d_ws, size_t ws_size,
                              hipStream_t stream) {
    const float* src  = (const float*)d_in[0];
    const float* dst  = (const float*)d_in[1];
    const float* attr = (const float*)d_in[2];
    const float* W1   = (const float*)d_in[3];
    const float* b1   = (const float*)d_in[4];
    const float* W2   = (const float*)d_in[5];
    const float* b2   = (const float*)d_in[6];
    const int*   gidx = (const int*)d_in[7];
    // d_in[8] = num_groups (constant 25000, baked in)

    float* weights_out = (float*)d_out;          // [E] (shape [E,1])
    float* logits_out  = (float*)d_out + E_N;    // [E]

    char* ws = (char*)d_ws;
    ushort* Wb  = (ushort*)ws;                          // 128*288*2 = 73728 B
    float*  seg = (float*)(ws + 73728);                 // 25000*4  = 100000 B
    float*  ex  = (float*)(ws + 73728 + 100000);        // 500000*4 = 2 MB (offset 16B-aligned)

    prep_kernel<<<(HIDN * KPAD + 255) / 256, 256, 0, stream>>>(W1, seg, Wb);

    const int nblk = (E_N + 255) / 256;   // 1954
    mlp_kernel<<<nblk, 256, 0, stream>>>(src, dst, attr, Wb, b1, W2, b2, gidx,
                                         logits_out, ex, seg);
    norm_kernel<<<nblk, 256, 0, stream>>>(ex, seg, gidx, weights_out);
}

// Round 2
// 550.948 us; speedup vs baseline: 1.1413x; 1.1413x over previous
//
#include <hip/hip_runtime.h>
#include <stdint.h>

// Problem constants (fixed by the reference)
#define E_N   500000
#define G_N   25000
#define HIDN  128
#define KIN   272
#define NKSTEP 9     // K padded 272 -> 288 = 9 * 32

typedef short bfrag_t __attribute__((ext_vector_type(8)));  // 8 bf16 = 4 VGPRs
typedef float accf4  __attribute__((ext_vector_type(4)));   // 4 f32 acc

__device__ __forceinline__ uint32_t pack2_bf16(float a, float b) {
    uint32_t ua = __builtin_bit_cast(uint32_t, a);
    uint32_t ub = __builtin_bit_cast(uint32_t, b);
    ua += 0x7FFFu + ((ua >> 16) & 1u);   // RNE
    ub += 0x7FFFu + ((ub >> 16) & 1u);
    return (ua >> 16) | (ub & 0xFFFF0000u);
}

// ---------------- prep: zero seg_sum; build Wb in MFMA B-fragment order.
// Wb[((s*8+b)*64 + lane)*8 + j] = bf16( W1[k][n] ), k = s*32 + (lane>>4)*8 + j,
// n = b*16 + (lane&15); zero-pad k >= 272. Total 9*8*64*8 = 36864 elements.
__global__ void prep_kernel(const float* __restrict__ W1, float* __restrict__ seg_sum,
                            ushort* __restrict__ Wb) {
    int t = blockIdx.x * 256 + threadIdx.x;   // grid = 144*256 = 36864 exactly
    if (t < G_N) seg_sum[t] = 0.0f;
    int j    = t & 7;
    int lane = (t >> 3) & 63;
    int sb   = t >> 9;          // s*8 + b
    int b    = sb & 7;
    int s    = sb >> 3;
    int k    = s * 32 + (lane >> 4) * 8 + j;
    int n    = b * 16 + (lane & 15);
    ushort v = 0;
    if (k < KIN) {
        uint32_t u = __builtin_bit_cast(uint32_t, W1[k * HIDN + n]);
        u += 0x7FFFu + ((u >> 16) & 1u);
        v = (ushort)(u >> 16);
    }
    Wb[t] = v;
}

// ---------------- main: fused MLP (GEMM1 + relu + GEMM2) + exp + segment-sum
// No LDS, no barriers. 4 waves/block, 32 rows/wave (2 a-tiles), full N=128.
// A-fragments loaded straight from global (8 consecutive f32 -> bf16 pack);
// B-fragments loaded from fragment-ordered Wb (coalesced, L2-resident).
__launch_bounds__(256, 3)
__global__ void mlp_kernel(const float* __restrict__ src, const float* __restrict__ dst,
                           const float* __restrict__ attr, const ushort* __restrict__ Wb,
                           const float* __restrict__ b1, const float* __restrict__ W2,
                           const float* __restrict__ b2, const int* __restrict__ gidx,
                           float* __restrict__ logits_out, float* __restrict__ ex_out,
                           float* __restrict__ seg_sum) {
    const int tid  = threadIdx.x;
    const int lane = tid & 63;
    const int wave = tid >> 6;
    const int m    = lane & 15;   // row-within-tile (A), col-within-tile (B/C)
    const int q    = lane >> 4;   // k-quad (A/B), row-quad (C)
    const int rowbase = blockIdx.x * 128 + wave * 32;

    const int  r0 = rowbase + m,  r1 = rowbase + 16 + m;
    const bool v0 = r0 < E_N,     v1 = r1 < E_N;

    accf4 acc[2][8];
    #pragma unroll
    for (int a = 0; a < 2; ++a)
        #pragma unroll
        for (int b = 0; b < 8; ++b)
            acc[a][b] = (accf4)(0.0f);

    #pragma unroll
    for (int s = 0; s < NKSTEP; ++s) {
        // B fragments: 8 coalesced 16B loads (L2-resident, 72 KB total)
        bfrag_t bf[8];
        #pragma unroll
        for (int b = 0; b < 8; ++b)
            bf[b] = *(const bfrag_t*)(Wb + (size_t)((s * 8 + b) * 64 + lane) * 8);

        // A fragments: lane reads 8 consecutive f32 of its row, packs to bf16
        bfrag_t af[2];
        #pragma unroll
        for (int a = 0; a < 2; ++a) {
            const int  rr = a ? r1 : r0;
            const bool vv = a ? v1 : v0;
            float4 x0 = {0.f, 0.f, 0.f, 0.f}, x1 = {0.f, 0.f, 0.f, 0.f};
            if (s < 8) {
                const float* base  = (s < 4) ? src : dst;
                const int coloff   = (s < 4) ? s * 32 : (s - 4) * 32;
                const float* p = base + (size_t)rr * 128 + coloff + q * 8;
                if (vv) { x0 = ((const float4*)p)[0]; x1 = ((const float4*)p)[1]; }
            } else {
                if (vv && q < 2) {   // k = 256 + q*8 + j ; valid only k < 272
                    const float* p = attr + (size_t)rr * 16 + q * 8;
                    x0 = ((const float4*)p)[0]; x1 = ((const float4*)p)[1];
                }
            }
            uint4 u;
            u.x = pack2_bf16(x0.x, x0.y);
            u.y = pack2_bf16(x0.z, x0.w);
            u.z = pack2_bf16(x1.x, x1.y);
            u.w = pack2_bf16(x1.z, x1.w);
            af[a] = *(bfrag_t*)&u;
        }

        #pragma unroll
        for (int b = 0; b < 8; ++b)
            #pragma unroll
            for (int a = 0; a < 2; ++a)
                acc[a][b] = __builtin_amdgcn_mfma_f32_16x16x32_bf16(af[a], bf[b], acc[a][b], 0, 0, 0);
    }

    // ---- epilogue: h = relu(acc + b1); logit = h . W2 + b2 (f32 throughout)
    float w2v[8], b1v[8];
    #pragma unroll
    for (int b = 0; b < 8; ++b) {
        w2v[b] = W2[b * 16 + m];
        b1v[b] = b1[b * 16 + m];
    }
    const float bias2 = b2[0];

    #pragma unroll
    for (int a = 0; a < 2; ++a) {
        float p4[4] = {0.f, 0.f, 0.f, 0.f};
        #pragma unroll
        for (int b = 0; b < 8; ++b)
            #pragma unroll
            for (int rr = 0; rr < 4; ++rr) {
                float h = acc[a][b][rr] + b1v[b];
                h = h > 0.f ? h : 0.f;
                p4[rr] += h * w2v[b];
            }
        #pragma unroll
        for (int rr = 0; rr < 4; ++rr) {
            float v = p4[rr];
            v += __shfl_xor(v, 1);   // reduce across the 16 column-lanes
            v += __shfl_xor(v, 2);
            v += __shfl_xor(v, 4);
            v += __shfl_xor(v, 8);
            if (m == 0) {
                int grow = rowbase + a * 16 + q * 4 + rr;
                if (grow < E_N) {
                    float logit = v + bias2;
                    logits_out[grow] = logit;
                    float ex = __expf(logit);   // no max-subtraction: |logit| < ~6
                    ex_out[grow] = ex;
                    atomicAdd(&seg_sum[gidx[grow]], ex);
                }
            }
        }
    }
}

// ---------------- normalize: weight = ex / seg_sum[g]
__global__ void norm_kernel(const float* __restrict__ ex, const float* __restrict__ seg_sum,
                            const int* __restrict__ gidx, float* __restrict__ wout) {
    int e = blockIdx.x * 256 + threadIdx.x;
    if (e < E_N) wout[e] = ex[e] / seg_sum[gidx[e]];
}

extern "C" void kernel_launch(void* const* d_in, const int* in_sizes, int n_in,
                              void* d_out, int out_size, void* d_ws, size_t ws_size,
                              hipStream_t stream) {
    const float* src  = (const float*)d_in[0];
    const float* dst  = (const float*)d_in[1];
    const float* attr = (const float*)d_in[2];
    const float* W1   = (const float*)d_in[3];
    const float* b1   = (const float*)d_in[4];
    const float* W2   = (const float*)d_in[5];
    const float* b2   = (const float*)d_in[6];
    const int*   gidx = (const int*)d_in[7];
    // d_in[8] = num_groups (constant 25000, baked in)

    float* weights_out = (float*)d_out;          // [E] (shape [E,1])
    float* logits_out  = (float*)d_out + E_N;    // [E]

    char* ws = (char*)d_ws;
    ushort* Wb  = (ushort*)ws;                          // 36864*2 = 73728 B
    float*  seg = (float*)(ws + 73728);                 // 25000*4 = 100000 B
    float*  ex  = (float*)(ws + 173728);                // 500000*4 = 2 MB

    prep_kernel<<<144, 256, 0, stream>>>(W1, seg, Wb);

    const int nblk = (E_N + 127) / 128;   // 3907 (128 rows/block)
    mlp_kernel<<<nblk, 256, 0, stream>>>(src, dst, attr, Wb, b1, W2, b2, gidx,
                                         logits_out, ex, seg);
    norm_kernel<<<(E_N + 255) / 256, 256, 0, stream>>>(ex, seg, gidx, weights_out);
}

// Round 3
// 537.931 us; speedup vs baseline: 1.1689x; 1.0242x over previous
//
#include <hip/hip_runtime.h>
#include <stdint.h>

// Problem constants (fixed by the reference)
#define E_N   500000
#define G_N   25000
#define HIDN  128
#define KIN   272
#define NKSTEP 9     // K padded 272 -> 288 = 9 * 32
#define WB_ELEMS 36864   // 9*8*64*8 bf16 fragment-ordered W1

typedef short bfrag_t __attribute__((ext_vector_type(8)));  // 8 bf16 = 4 VGPRs
typedef float accf4  __attribute__((ext_vector_type(4)));   // 4 f32 acc

// round-to-nearest (ties away) f32->bf16 pair pack: 3 VALU ops
__device__ __forceinline__ uint32_t pack2_bf16(float a, float b) {
    uint32_t ua = __builtin_bit_cast(uint32_t, a) + 0x8000u;
    uint32_t ub = __builtin_bit_cast(uint32_t, b) + 0x8000u;
    // v_perm_b32: S0=ub, S1=ua; result = hi16(ua) | hi16(ub)<<16
    return __builtin_amdgcn_perm(ub, ua, 0x07060302u);
}

// ---------------- prep: zero seg_sum; build Wb in MFMA B-fragment order (RNE).
// Wb[((s*8+b)*64 + lane)*8 + j] = bf16( W1[k][n] ), k = s*32 + (lane>>4)*8 + j,
// n = b*16 + (lane&15); zero-pad k >= 272.
__global__ void prep_kernel(const float* __restrict__ W1, float* __restrict__ seg_sum,
                            ushort* __restrict__ Wb) {
    int t = blockIdx.x * 256 + threadIdx.x;   // grid = 144*256 = 36864 exactly
    if (t < G_N) seg_sum[t] = 0.0f;
    int j    = t & 7;
    int lane = (t >> 3) & 63;
    int sb   = t >> 9;          // s*8 + b
    int b    = sb & 7;
    int s    = sb >> 3;
    int k    = s * 32 + (lane >> 4) * 8 + j;
    int n    = b * 16 + (lane & 15);
    ushort v = 0;
    if (k < KIN) {
        uint32_t u = __builtin_bit_cast(uint32_t, W1[k * HIDN + n]);
        u += 0x7FFFu + ((u >> 16) & 1u);
        v = (ushort)(u >> 16);
    }
    Wb[t] = v;
}

// ---------------- main: fused MLP (GEMM1 + relu + GEMM2) + exp + segment-sum
// Block = 512 threads (8 waves), 32 rows/wave -> 256 rows/block.
// B staged once into LDS (fragment order, 72 KB) -> ds_read_b128 in the K-loop;
// vmcnt queue carries only the streaming A loads (deep prefetch). One barrier.
__launch_bounds__(512, 4)
__global__ void mlp_kernel(const float* __restrict__ src, const float* __restrict__ dst,
                           const float* __restrict__ attr, const ushort* __restrict__ Wb,
                           const float* __restrict__ b1, const float* __restrict__ W2,
                           const float* __restrict__ b2, const int* __restrict__ gidx,
                           float* __restrict__ logits_out, float* __restrict__ ex_out,
                           float* __restrict__ seg_sum) {
    __shared__ __align__(16) ushort Blds[WB_ELEMS];   // 73728 B

    const int tid  = threadIdx.x;
    const int lane = tid & 63;
    const int wave = tid >> 6;
    const int m    = lane & 15;   // row-within-tile (A), col-within-tile (B/C)
    const int q    = lane >> 4;   // k-quad (A/B), row-quad (C)
    const int rowbase = blockIdx.x * 256 + wave * 32;

    // ---- stage B fragments to LDS: 4608 x 16B chunks, 9 per thread
    #pragma unroll
    for (int i = 0; i < 9; ++i) {
        int c = i * 512 + tid;
        ((uint4*)Blds)[c] = ((const uint4*)Wb)[c];
    }
    __syncthreads();

    const int  r0 = rowbase + m,  r1 = rowbase + 16 + m;
    const bool v0 = r0 < E_N,     v1 = r1 < E_N;

    accf4 acc[2][8];
    #pragma unroll
    for (int a = 0; a < 2; ++a)
        #pragma unroll
        for (int b = 0; b < 8; ++b)
            acc[a][b] = (accf4)(0.0f);

    #pragma unroll
    for (int s = 0; s < NKSTEP; ++s) {
        // A fragments: lane reads 8 consecutive f32 of its row, packs to bf16
        bfrag_t af[2];
        #pragma unroll
        for (int a = 0; a < 2; ++a) {
            const int  rr = a ? r1 : r0;
            const bool vv = a ? v1 : v0;
            float4 x0 = {0.f, 0.f, 0.f, 0.f}, x1 = {0.f, 0.f, 0.f, 0.f};
            if (s < 8) {
                const float* base  = (s < 4) ? src : dst;
                const int coloff   = (s < 4) ? s * 32 : (s - 4) * 32;
                const float* p = base + (size_t)rr * 128 + coloff + q * 8;
                if (vv) { x0 = ((const float4*)p)[0]; x1 = ((const float4*)p)[1]; }
            } else {
                if (vv && q < 2) {   // k = 256 + q*8 + j ; valid only k < 272
                    const float* p = attr + (size_t)rr * 16 + q * 8;
                    x0 = ((const float4*)p)[0]; x1 = ((const float4*)p)[1];
                }
            }
            uint4 u;
            u.x = pack2_bf16(x0.x, x0.y);
            u.y = pack2_bf16(x0.z, x0.w);
            u.z = pack2_bf16(x1.x, x1.y);
            u.w = pack2_bf16(x1.z, x1.w);
            af[a] = *(bfrag_t*)&u;
        }

        // B fragments from LDS + MFMA
        #pragma unroll
        for (int b = 0; b < 8; ++b) {
            bfrag_t bf = *(const bfrag_t*)&Blds[(size_t)((s * 8 + b) * 64 + lane) * 8];
            #pragma unroll
            for (int a = 0; a < 2; ++a)
                acc[a][b] = __builtin_amdgcn_mfma_f32_16x16x32_bf16(af[a], bf, acc[a][b], 0, 0, 0);
        }
    }

    // ---- epilogue: h = relu(acc + b1); logit = h . W2 + b2 (f32 throughout)
    float w2v[8], b1v[8];
    #pragma unroll
    for (int b = 0; b < 8; ++b) {
        w2v[b] = W2[b * 16 + m];
        b1v[b] = b1[b * 16 + m];
    }
    const float bias2 = b2[0];

    #pragma unroll
    for (int a = 0; a < 2; ++a) {
        float p4[4] = {0.f, 0.f, 0.f, 0.f};
        #pragma unroll
        for (int b = 0; b < 8; ++b)
            #pragma unroll
            for (int rr = 0; rr < 4; ++rr) {
                float h = acc[a][b][rr] + b1v[b];
                h = h > 0.f ? h : 0.f;
                p4[rr] += h * w2v[b];
            }
        #pragma unroll
        for (int rr = 0; rr < 4; ++rr) {
            float v = p4[rr];
            v += __shfl_xor(v, 1);   // reduce across the 16 column-lanes
            v += __shfl_xor(v, 2);
            v += __shfl_xor(v, 4);
            v += __shfl_xor(v, 8);
            if (m == 0) {
                int grow = rowbase + a * 16 + q * 4 + rr;
                if (grow < E_N) {
                    float logit = v + bias2;
                    logits_out[grow] = logit;
                    float ex = __expf(logit);   // no max-subtraction: |logit| < ~6
                    ex_out[grow] = ex;
                    atomicAdd(&seg_sum[gidx[grow]], ex);
                }
            }
        }
    }
}

// ---------------- normalize: weight = ex / seg_sum[g]
__global__ void norm_kernel(const float* __restrict__ ex, const float* __restrict__ seg_sum,
                            const int* __restrict__ gidx, float* __restrict__ wout) {
    int e = blockIdx.x * 256 + threadIdx.x;
    if (e < E_N) wout[e] = ex[e] / seg_sum[gidx[e]];
}

extern "C" void kernel_launch(void* const* d_in, const int* in_sizes, int n_in,
                              void* d_out, int out_size, void* d_ws, size_t ws_size,
                              hipStream_t stream) {
    const float* src  = (const float*)d_in[0];
    const float* dst  = (const float*)d_in[1];
    const float* attr = (const float*)d_in[2];
    const float* W1   = (const float*)d_in[3];
    const float* b1   = (const float*)d_in[4];
    const float* W2   = (const float*)d_in[5];
    const float* b2   = (const float*)d_in[6];
    const int*   gidx = (const int*)d_in[7];
    // d_in[8] = num_groups (constant 25000, baked in)

    float* weights_out = (float*)d_out;          // [E] (shape [E,1])
    float* logits_out  = (float*)d_out + E_N;    // [E]

    char* ws = (char*)d_ws;
    ushort* Wb  = (ushort*)ws;                          // 36864*2 = 73728 B
    float*  seg = (float*)(ws + 73728);                 // 25000*4 = 100000 B
    float*  ex  = (float*)(ws + 173728);                // 500000*4 = 2 MB

    prep_kernel<<<144, 256, 0, stream>>>(W1, seg, Wb);

    const int nblk = (E_N + 255) / 256;   // 1954 (256 rows/block)
    mlp_kernel<<<nblk, 512, 0, stream>>>(src, dst, attr, Wb, b1, W2, b2, gidx,
                                         logits_out, ex, seg);
    norm_kernel<<<(E_N + 255) / 256, 256, 0, stream>>>(ex, seg, gidx, weights_out);
}